// Round 1
// baseline (296.377 us; speedup 1.0000x reference)
//
#include <hip/hip_runtime.h>
#include <math.h>

// Problem constants
#define NPTS 200000
#define LNEPS 1e-6f

typedef unsigned short u16;
typedef __attribute__((ext_vector_type(4))) float  f4;
typedef __attribute__((ext_vector_type(8))) short  s8;

__device__ __forceinline__ u16 f2b(float f) {
    union { float f; unsigned u; } v; v.f = f;
    unsigned r = v.u + 0x7fffu + ((v.u >> 16) & 1u);   // round-to-nearest-even
    return (u16)(r >> 16);
}

__device__ __forceinline__ float gelu_f(float v) {
    return 0.5f * v * (1.0f + erff(v * 0.70710678118654752440f));
}

// ---------------------------------------------------------------------------
// K0: repack weights to bf16 MFMA B-fragment order.
// B-frag layout for mfma_f32_16x16x32_bf16: lane l holds B[k][n] with
// n = 16*nt + (l&15), k = 32*ks + (l>>4)*8 + j  (j = 0..7 contiguous).
// Storage: frag[((nt*KS + ks)*64 + l)*8 + j]
// Also zeroes the sentinel row h1[NPTS] (reference's h_pad row).
// ---------------------------------------------------------------------------
__global__ __launch_bounds__(256) void k0_convw(
    const float* __restrict__ W1, const float* __restrict__ W2,
    const float* __restrict__ W3,
    u16* __restrict__ W1f, u16* __restrict__ W2f, u16* __restrict__ W3f,
    u16* __restrict__ h1)
{
    int t = blockIdx.x * 256 + threadIdx.x;
    if (t < 16384) {                       // W1f: nt(4) ks(8) l(64) j(8)
        int j = t & 7, l = (t >> 3) & 63, ks = (t >> 9) & 7, nt = t >> 12;
        int k = 32 * ks + (l >> 4) * 8 + j;
        int n = 16 * nt + (l & 15);
        W1f[t] = f2b(W1[k * 64 + n]);
    }
    if (t < 36864) {                       // W2f: kk(9) x { nt(4) ks(2) l(64) j(8) }
        int kk = t >> 12;
        int r = t & 4095;
        int j = r & 7, l = (r >> 3) & 63, ks = (r >> 9) & 1, nt = r >> 10;
        int k = 32 * ks + (l >> 4) * 8 + j;
        int n = 16 * nt + (l & 15);
        W2f[t] = f2b(W2[(kk * 64 + k) * 64 + n]);
    }
    if (t < 16384) {                       // W3f: nt(16) ks(2) l(64) j(8)
        int j = t & 7, l = (t >> 3) & 63, ks = (t >> 9) & 1, nt = t >> 10;
        int k = 32 * ks + (l >> 4) * 8 + j;
        int n = 16 * nt + (l & 15);
        W3f[t] = f2b(W3[k * 256 + n]);
    }
    if (t < 64) h1[(long)NPTS * 64 + t] = 0;   // sentinel zero row
}

// ---------------------------------------------------------------------------
// K1: conv1 (x @ W1) + LN + GELU -> h1 (bf16, [NPTS+1][64])
// 64 rows/block, 4 waves, each wave one 16-row M-tile, 4 N-tiles, 8 K-steps.
// ---------------------------------------------------------------------------
__global__ __launch_bounds__(256) void k1_conv1(
    const float* __restrict__ x, const u16* __restrict__ W1f,
    const float* __restrict__ g1, const float* __restrict__ b1,
    u16* __restrict__ h1)
{
    int tid = threadIdx.x;
    int w = tid >> 6, l = tid & 63, lg = l >> 4, lr = l & 15;
    long base = (long)blockIdx.x * 64 + w * 16;
    const float* xrow = x + (base + lr) * 256;

    f4 acc[4] = {};
    #pragma unroll
    for (int ks = 0; ks < 8; ++ks) {
        int c0 = 32 * ks + lg * 8;
        f4 a0 = *(const f4*)(xrow + c0);
        f4 a1 = *(const f4*)(xrow + c0 + 4);
        s8 a;
        a[0] = (short)f2b(a0[0]); a[1] = (short)f2b(a0[1]);
        a[2] = (short)f2b(a0[2]); a[3] = (short)f2b(a0[3]);
        a[4] = (short)f2b(a1[0]); a[5] = (short)f2b(a1[1]);
        a[6] = (short)f2b(a1[2]); a[7] = (short)f2b(a1[3]);
        #pragma unroll
        for (int nt = 0; nt < 4; ++nt) {
            s8 b = *(const s8*)(W1f + ((nt * 8 + ks) * 64 + l) * 8);
            acc[nt] = __builtin_amdgcn_mfma_f32_16x16x32_bf16(a, b, acc[nt], 0, 0, 0);
        }
    }

    // LN(64) + GELU.  D layout: col = 16*nt + lr, row(tile) = lg*4 + r.
    #pragma unroll
    for (int r = 0; r < 4; ++r) {
        float sv = 0.f, qv = 0.f;
        #pragma unroll
        for (int nt = 0; nt < 4; ++nt) { float v = acc[nt][r]; sv += v; qv += v * v; }
        #pragma unroll
        for (int m = 1; m < 16; m <<= 1) { sv += __shfl_xor(sv, m); qv += __shfl_xor(qv, m); }
        float mu  = sv * (1.0f / 64.0f);
        float var = qv * (1.0f / 64.0f) - mu * mu;
        float rs  = rsqrtf(var + LNEPS);
        long row = base + lg * 4 + r;
        #pragma unroll
        for (int nt = 0; nt < 4; ++nt) {
            int col = 16 * nt + lr;
            float v = (acc[nt][r] - mu) * rs * g1[col] + b1[col];
            h1[row * 64 + col] = f2b(gelu_f(v));
        }
    }
}

// ---------------------------------------------------------------------------
// K2: gather + conv2 + LN + GELU  (then via LDS)  conv3 + LN + residual + GELU
// 64 rows/block, 4 waves. h1 gathers are L2/L3-resident (25.6 MB bf16).
// ---------------------------------------------------------------------------
__global__ __launch_bounds__(256) void k2_fused(
    const u16* __restrict__ h1, const u16* __restrict__ W2f,
    const u16* __restrict__ W3f, const float* __restrict__ x,
    const float* __restrict__ g2, const float* __restrict__ b2,
    const float* __restrict__ g3, const float* __restrict__ b3,
    const int* __restrict__ nidx, float* __restrict__ out)
{
    __shared__ __align__(16) u16 A3[4][16][72];   // per-wave h2 tile, +8 pad
    int tid = threadIdx.x;
    int w = tid >> 6, l = tid & 63, lg = l >> 4, lr = l & 15;
    long base = (long)blockIdx.x * 64 + w * 16;
    long rowa = base + lr;

    // ---- conv2: sum over 9 kernel taps of gathered h1 rows @ W2[k] ----
    f4 acc2[4] = {};
    #pragma unroll
    for (int k = 0; k < 9; ++k) {
        int idx = nidx[(long)k * NPTS + rowa];        // sentinel NPTS -> zero row
        const u16* arow = h1 + (long)idx * 64;
        #pragma unroll
        for (int ks = 0; ks < 2; ++ks) {
            s8 a = *(const s8*)(arow + 32 * ks + lg * 8);
            #pragma unroll
            for (int nt = 0; nt < 4; ++nt) {
                s8 b = *(const s8*)(W2f + (long)k * 4096 + ((nt * 2 + ks) * 64 + l) * 8);
                acc2[nt] = __builtin_amdgcn_mfma_f32_16x16x32_bf16(a, b, acc2[nt], 0, 0, 0);
            }
        }
    }

    // ---- LN(64) + GELU -> LDS tile (bf16) ----
    #pragma unroll
    for (int r = 0; r < 4; ++r) {
        float sv = 0.f, qv = 0.f;
        #pragma unroll
        for (int nt = 0; nt < 4; ++nt) { float v = acc2[nt][r]; sv += v; qv += v * v; }
        #pragma unroll
        for (int m = 1; m < 16; m <<= 1) { sv += __shfl_xor(sv, m); qv += __shfl_xor(qv, m); }
        float mu  = sv * (1.0f / 64.0f);
        float var = qv * (1.0f / 64.0f) - mu * mu;
        float rs  = rsqrtf(var + LNEPS);
        #pragma unroll
        for (int nt = 0; nt < 4; ++nt) {
            int col = 16 * nt + lr;
            float v = (acc2[nt][r] - mu) * rs * g2[col] + b2[col];
            A3[w][lg * 4 + r][col] = f2b(gelu_f(v));
        }
    }
    __syncthreads();

    // ---- conv3: (16x64 tile) @ W3(64x256) ----
    s8 a0 = *(const s8*)(&A3[w][lr][lg * 8]);        // ks=0
    s8 a1 = *(const s8*)(&A3[w][lr][32 + lg * 8]);   // ks=1
    f4 acc3[16] = {};
    #pragma unroll
    for (int nt = 0; nt < 16; ++nt) {
        s8 b0 = *(const s8*)(W3f + ((nt * 2 + 0) * 64 + l) * 8);
        s8 b1 = *(const s8*)(W3f + ((nt * 2 + 1) * 64 + l) * 8);
        acc3[nt] = __builtin_amdgcn_mfma_f32_16x16x32_bf16(a0, b0, acc3[nt], 0, 0, 0);
        acc3[nt] = __builtin_amdgcn_mfma_f32_16x16x32_bf16(a1, b1, acc3[nt], 0, 0, 0);
    }

    // ---- LN(256) + residual + GELU -> out ----
    #pragma unroll
    for (int r = 0; r < 4; ++r) {
        float sv = 0.f, qv = 0.f;
        #pragma unroll
        for (int nt = 0; nt < 16; ++nt) { float v = acc3[nt][r]; sv += v; qv += v * v; }
        #pragma unroll
        for (int m = 1; m < 16; m <<= 1) { sv += __shfl_xor(sv, m); qv += __shfl_xor(qv, m); }
        float mu  = sv * (1.0f / 256.0f);
        float var = qv * (1.0f / 256.0f) - mu * mu;
        float rs  = rsqrtf(var + LNEPS);
        long row = base + lg * 4 + r;
        const float* xr = x + row * 256;
        float* outr = out + row * 256;
        #pragma unroll
        for (int nt = 0; nt < 16; ++nt) {
            int col = 16 * nt + lr;
            float v = (acc3[nt][r] - mu) * rs * g3[col] + b3[col];
            v += xr[col];
            outr[col] = gelu_f(v);
        }
    }
}

// ---------------------------------------------------------------------------
extern "C" void kernel_launch(void* const* d_in, const int* in_sizes, int n_in,
                              void* d_out, int out_size, void* d_ws, size_t ws_size,
                              hipStream_t stream)
{
    const float* x  = (const float*)d_in[0];
    const float* W1 = (const float*)d_in[1];
    const float* W2 = (const float*)d_in[2];
    const float* W3 = (const float*)d_in[3];
    const float* g1 = (const float*)d_in[4];
    const float* b1 = (const float*)d_in[5];
    const float* g2 = (const float*)d_in[6];
    const float* b2 = (const float*)d_in[7];
    const float* g3 = (const float*)d_in[8];
    const float* b3 = (const float*)d_in[9];
    const int* nidx = (const int*)d_in[10];
    float* out = (float*)d_out;

    char* ws = (char*)d_ws;
    u16* W1f = (u16*)(ws);                 //  32768 B
    u16* W2f = (u16*)(ws + 32768);         //  73728 B
    u16* W3f = (u16*)(ws + 106496);        //  32768 B
    u16* h1  = (u16*)(ws + 139264);        //  (NPTS+1)*64*2 = 25,600,128 B

    hipLaunchKernelGGL(k0_convw, dim3(144), dim3(256), 0, stream,
                       W1, W2, W3, W1f, W2f, W3f, h1);
    hipLaunchKernelGGL(k1_conv1, dim3(3125), dim3(256), 0, stream,
                       x, W1f, g1, b1, h1);
    hipLaunchKernelGGL(k2_fused, dim3(3125), dim3(256), 0, stream,
                       h1, W2f, W3f, x, g2, b2, g3, b3, nidx, out);
}

// Round 2
// 214.621 us; speedup vs baseline: 1.3809x; 1.3809x over previous
//
#include <hip/hip_runtime.h>
#include <math.h>

// Problem constants
#define NPTS 200000
#define LNEPS 1e-6f

typedef unsigned short u16;
typedef __attribute__((ext_vector_type(4))) float  f4;
typedef __attribute__((ext_vector_type(8))) short  s8;

__device__ __forceinline__ u16 f2b(float f) {
    union { float f; unsigned u; } v; v.f = f;
    unsigned r = v.u + 0x7fffu + ((v.u >> 16) & 1u);   // round-to-nearest-even
    return (u16)(r >> 16);
}

// tanh-form GELU: max abs deviation from exact erf-GELU ~1e-3, far below the
// bf16-scale pass threshold. Uses HW v_exp_f32 (2^x) + v_rcp_f32.
// Clamp u at +15 so exp2 can't overflow to inf (inf/inf = NaN); negative side
// underflows to 0 -> tanh = -1 exactly, which is correct.
__device__ __forceinline__ float gelu_f(float v) {
    float u = v * (0.7978845608028654f + 0.035677408136300125f * v * v);
    u = fminf(u, 15.0f);
    float e = __builtin_amdgcn_exp2f(u * 2.8853900817779268f);  // exp(2u)
    return 0.5f * v * (1.0f + (e - 1.0f) * __builtin_amdgcn_rcpf(e + 1.0f));
}

// ---------------------------------------------------------------------------
// K0: repack weights to bf16 MFMA B-fragment order.
// B-frag layout for mfma_f32_16x16x32_bf16: lane l holds B[k][n] with
// n = 16*nt + (l&15), k = 32*ks + (l>>4)*8 + j  (j = 0..7 contiguous).
// Storage: frag[((nt*KS + ks)*64 + l)*8 + j]
// Also zeroes the sentinel row h1[NPTS] (reference's h_pad row).
// ---------------------------------------------------------------------------
__global__ __launch_bounds__(256) void k0_convw(
    const float* __restrict__ W1, const float* __restrict__ W2,
    const float* __restrict__ W3,
    u16* __restrict__ W1f, u16* __restrict__ W2f, u16* __restrict__ W3f,
    u16* __restrict__ h1)
{
    int t = blockIdx.x * 256 + threadIdx.x;
    if (t < 16384) {                       // W1f: nt(4) ks(8) l(64) j(8)
        int j = t & 7, l = (t >> 3) & 63, ks = (t >> 9) & 7, nt = t >> 12;
        int k = 32 * ks + (l >> 4) * 8 + j;
        int n = 16 * nt + (l & 15);
        W1f[t] = f2b(W1[k * 64 + n]);
    }
    if (t < 36864) {                       // W2f: kk(9) x { nt(4) ks(2) l(64) j(8) }
        int kk = t >> 12;
        int r = t & 4095;
        int j = r & 7, l = (r >> 3) & 63, ks = (r >> 9) & 1, nt = r >> 10;
        int k = 32 * ks + (l >> 4) * 8 + j;
        int n = 16 * nt + (l & 15);
        W2f[t] = f2b(W2[(kk * 64 + k) * 64 + n]);
    }
    if (t < 16384) {                       // W3f: nt(16) ks(2) l(64) j(8)
        int j = t & 7, l = (t >> 3) & 63, ks = (t >> 9) & 1, nt = t >> 10;
        int k = 32 * ks + (l >> 4) * 8 + j;
        int n = 16 * nt + (l & 15);
        W3f[t] = f2b(W3[k * 256 + n]);
    }
    if (t < 64) h1[(long)NPTS * 64 + t] = 0;   // sentinel zero row
}

// ---------------------------------------------------------------------------
// K1: conv1 (x @ W1) + LN + GELU -> h1 (bf16, [NPTS+1][64])
// 64 rows/block, 4 waves, each wave one 16-row M-tile, 4 N-tiles, 8 K-steps.
// All 16 f4 x-loads issued before convert+MFMA (MLP).
// ---------------------------------------------------------------------------
__global__ __launch_bounds__(256) void k1_conv1(
    const float* __restrict__ x, const u16* __restrict__ W1f,
    const float* __restrict__ g1, const float* __restrict__ b1,
    u16* __restrict__ h1)
{
    int tid = threadIdx.x;
    int w = tid >> 6, l = tid & 63, lg = l >> 4, lr = l & 15;
    long base = (long)blockIdx.x * 64 + w * 16;
    const float* xrow = x + (base + lr) * 256;

    f4 xa[16];
    #pragma unroll
    for (int ks = 0; ks < 8; ++ks) {
        xa[2 * ks]     = *(const f4*)(xrow + 32 * ks + lg * 8);
        xa[2 * ks + 1] = *(const f4*)(xrow + 32 * ks + lg * 8 + 4);
    }

    f4 acc[4] = {};
    #pragma unroll
    for (int ks = 0; ks < 8; ++ks) {
        f4 a0 = xa[2 * ks], a1 = xa[2 * ks + 1];
        s8 a;
        a[0] = (short)f2b(a0[0]); a[1] = (short)f2b(a0[1]);
        a[2] = (short)f2b(a0[2]); a[3] = (short)f2b(a0[3]);
        a[4] = (short)f2b(a1[0]); a[5] = (short)f2b(a1[1]);
        a[6] = (short)f2b(a1[2]); a[7] = (short)f2b(a1[3]);
        #pragma unroll
        for (int nt = 0; nt < 4; ++nt) {
            s8 b = *(const s8*)(W1f + ((nt * 8 + ks) * 64 + l) * 8);
            acc[nt] = __builtin_amdgcn_mfma_f32_16x16x32_bf16(a, b, acc[nt], 0, 0, 0);
        }
    }

    // LN(64) + GELU.  D layout: col = 16*nt + lr, row(tile) = lg*4 + r.
    #pragma unroll
    for (int r = 0; r < 4; ++r) {
        float sv = 0.f, qv = 0.f;
        #pragma unroll
        for (int nt = 0; nt < 4; ++nt) { float v = acc[nt][r]; sv += v; qv += v * v; }
        #pragma unroll
        for (int m = 1; m < 16; m <<= 1) { sv += __shfl_xor(sv, m); qv += __shfl_xor(qv, m); }
        float mu  = sv * (1.0f / 64.0f);
        float var = qv * (1.0f / 64.0f) - mu * mu;
        float rs  = rsqrtf(var + LNEPS);
        long row = base + lg * 4 + r;
        #pragma unroll
        for (int nt = 0; nt < 4; ++nt) {
            int col = 16 * nt + lr;
            float v = (acc[nt][r] - mu) * rs * g1[col] + b1[col];
            h1[row * 64 + col] = f2b(gelu_f(v));
        }
    }
}

// ---------------------------------------------------------------------------
// K2: gather + conv2 + LN + GELU  (then via LDS)  conv3 + LN + residual + GELU
// 64 rows/block, 4 waves. All 9 idx + all 18 gather loads hoisted ahead of
// the MFMAs so the random-access latency overlaps (18 loads in flight/wave).
// ---------------------------------------------------------------------------
__global__ __launch_bounds__(256) void k2_fused(
    const u16* __restrict__ h1, const u16* __restrict__ W2f,
    const u16* __restrict__ W3f, const float* __restrict__ x,
    const float* __restrict__ g2, const float* __restrict__ b2,
    const float* __restrict__ g3, const float* __restrict__ b3,
    const int* __restrict__ nidx, float* __restrict__ out)
{
    __shared__ __align__(16) u16 A3[4][16][72];   // per-wave h2 tile, +8 pad
    int tid = threadIdx.x;
    int w = tid >> 6, l = tid & 63, lg = l >> 4, lr = l & 15;
    long base = (long)blockIdx.x * 64 + w * 16;
    long rowa = base + lr;

    // ---- all tap indices, then all gather loads (full MLP) ----
    int idxs[9];
    #pragma unroll
    for (int k = 0; k < 9; ++k) idxs[k] = nidx[(long)k * NPTS + rowa];

    s8 afr[9][2];
    #pragma unroll
    for (int k = 0; k < 9; ++k) {
        const u16* arow = h1 + (long)idxs[k] * 64;
        afr[k][0] = *(const s8*)(arow + lg * 8);
        afr[k][1] = *(const s8*)(arow + 32 + lg * 8);
    }

    // ---- conv2: sum over 9 taps ----
    f4 acc2[4] = {};
    #pragma unroll
    for (int k = 0; k < 9; ++k) {
        #pragma unroll
        for (int ks = 0; ks < 2; ++ks) {
            #pragma unroll
            for (int nt = 0; nt < 4; ++nt) {
                s8 b = *(const s8*)(W2f + (long)k * 4096 + ((nt * 2 + ks) * 64 + l) * 8);
                acc2[nt] = __builtin_amdgcn_mfma_f32_16x16x32_bf16(afr[k][ks], b, acc2[nt], 0, 0, 0);
            }
        }
    }

    // ---- LN(64) + GELU -> LDS tile (bf16) ----
    #pragma unroll
    for (int r = 0; r < 4; ++r) {
        float sv = 0.f, qv = 0.f;
        #pragma unroll
        for (int nt = 0; nt < 4; ++nt) { float v = acc2[nt][r]; sv += v; qv += v * v; }
        #pragma unroll
        for (int m = 1; m < 16; m <<= 1) { sv += __shfl_xor(sv, m); qv += __shfl_xor(qv, m); }
        float mu  = sv * (1.0f / 64.0f);
        float var = qv * (1.0f / 64.0f) - mu * mu;
        float rs  = rsqrtf(var + LNEPS);
        #pragma unroll
        for (int nt = 0; nt < 4; ++nt) {
            int col = 16 * nt + lr;
            float v = (acc2[nt][r] - mu) * rs * g2[col] + b2[col];
            A3[w][lg * 4 + r][col] = f2b(gelu_f(v));
        }
    }
    __syncthreads();

    // ---- conv3: (16x64 tile) @ W3(64x256) ----
    s8 a0 = *(const s8*)(&A3[w][lr][lg * 8]);        // ks=0
    s8 a1 = *(const s8*)(&A3[w][lr][32 + lg * 8]);   // ks=1
    f4 acc3[16] = {};
    #pragma unroll
    for (int nt = 0; nt < 16; ++nt) {
        s8 b0 = *(const s8*)(W3f + ((nt * 2 + 0) * 64 + l) * 8);
        s8 b1 = *(const s8*)(W3f + ((nt * 2 + 1) * 64 + l) * 8);
        acc3[nt] = __builtin_amdgcn_mfma_f32_16x16x32_bf16(a0, b0, acc3[nt], 0, 0, 0);
        acc3[nt] = __builtin_amdgcn_mfma_f32_16x16x32_bf16(a1, b1, acc3[nt], 0, 0, 0);
    }

    // ---- LN(256) + residual + GELU -> out ----
    #pragma unroll
    for (int r = 0; r < 4; ++r) {
        float sv = 0.f, qv = 0.f;
        #pragma unroll
        for (int nt = 0; nt < 16; ++nt) { float v = acc3[nt][r]; sv += v; qv += v * v; }
        #pragma unroll
        for (int m = 1; m < 16; m <<= 1) { sv += __shfl_xor(sv, m); qv += __shfl_xor(qv, m); }
        float mu  = sv * (1.0f / 256.0f);
        float var = qv * (1.0f / 256.0f) - mu * mu;
        float rs  = rsqrtf(var + LNEPS);
        long row = base + lg * 4 + r;
        const float* xr = x + row * 256;
        float* outr = out + row * 256;
        #pragma unroll
        for (int nt = 0; nt < 16; ++nt) {
            int col = 16 * nt + lr;
            float v = (acc3[nt][r] - mu) * rs * g3[col] + b3[col];
            v += xr[col];
            outr[col] = gelu_f(v);
        }
    }
}

// ---------------------------------------------------------------------------
extern "C" void kernel_launch(void* const* d_in, const int* in_sizes, int n_in,
                              void* d_out, int out_size, void* d_ws, size_t ws_size,
                              hipStream_t stream)
{
    const float* x  = (const float*)d_in[0];
    const float* W1 = (const float*)d_in[1];
    const float* W2 = (const float*)d_in[2];
    const float* W3 = (const float*)d_in[3];
    const float* g1 = (const float*)d_in[4];
    const float* b1 = (const float*)d_in[5];
    const float* g2 = (const float*)d_in[6];
    const float* b2 = (const float*)d_in[7];
    const float* g3 = (const float*)d_in[8];
    const float* b3 = (const float*)d_in[9];
    const int* nidx = (const int*)d_in[10];
    float* out = (float*)d_out;

    char* ws = (char*)d_ws;
    u16* W1f = (u16*)(ws);                 //  32768 B
    u16* W2f = (u16*)(ws + 32768);         //  73728 B
    u16* W3f = (u16*)(ws + 106496);        //  32768 B
    u16* h1  = (u16*)(ws + 139264);        //  (NPTS+1)*64*2 = 25,600,128 B

    hipLaunchKernelGGL(k0_convw, dim3(144), dim3(256), 0, stream,
                       W1, W2, W3, W1f, W2f, W3f, h1);
    hipLaunchKernelGGL(k1_conv1, dim3(3125), dim3(256), 0, stream,
                       x, W1f, g1, b1, h1);
    hipLaunchKernelGGL(k2_fused, dim3(3125), dim3(256), 0, stream,
                       h1, W2f, W3f, x, g2, b2, g3, b3, nidx, out);
}